// Round 1
// baseline (527.730 us; speedup 1.0000x reference)
//
#include <hip/hip_runtime.h>
#include <hip/hip_bf16.h>

// Deformable attention (Deformable-DETR) on MI355X.
// Static problem: B=8, NQ=900, E=256, H=8, L=4, P=4, dh=32, NV=19560
// levels (h,w): (92,160) (46,80) (23,40) (12,20); starts 0,14720,18400,19320

#define B_   8
#define NQ_  900
#define E_   256
#define H_   8
#define NV_  19560

// ---------------------------------------------------------------- K1: params
// off = query@Ws + bs  (256 cols), logits = query@Wa + ba (128 cols),
// softmax over each h's 16 logits. 4 query rows per block, 128 threads.
__global__ __launch_bounds__(128) void k_params(
    const float* __restrict__ query, const float* __restrict__ Ws,
    const float* __restrict__ bs, const float* __restrict__ Wa,
    const float* __restrict__ ba, float* __restrict__ off_out,
    float* __restrict__ attn_out)
{
    __shared__ float sq[4 * 256];
    __shared__ float slog[4 * 128];
    const int t = threadIdx.x;
    const int row0 = blockIdx.x * 4;      // flat (b*NQ+q) base
    const float4* qsrc = (const float4*)(query + row0 * 256);
    for (int i = t; i < 256; i += 128) ((float4*)sq)[i] = qsrc[i];
    __syncthreads();

    float a0[4] = {0,0,0,0}, a1[4] = {0,0,0,0}, a2[4] = {0,0,0,0};
    for (int k = 0; k < 256; ++k) {
        const float w0 = Ws[k * 256 + t];
        const float w1 = Ws[k * 256 + t + 128];
        const float w2 = Wa[k * 128 + t];
#pragma unroll
        for (int r = 0; r < 4; ++r) {
            const float q = sq[r * 256 + k];
            a0[r] = fmaf(q, w0, a0[r]);
            a1[r] = fmaf(q, w1, a1[r]);
            a2[r] = fmaf(q, w2, a2[r]);
        }
    }
    const float b0 = bs[t], b1 = bs[t + 128], b2 = ba[t];
#pragma unroll
    for (int r = 0; r < 4; ++r) {
        off_out[(row0 + r) * 256 + t]       = a0[r] + b0;
        off_out[(row0 + r) * 256 + t + 128] = a1[r] + b1;
        slog[r * 128 + t]                   = a2[r] + b2;
    }
    __syncthreads();
    if (t < 32) {                         // 4 rows x 8 heads
        const int r = t >> 3, h = t & 7;
        const float* pl = slog + r * 128 + h * 16;
        float m = pl[0];
#pragma unroll
        for (int j = 1; j < 16; ++j) m = fmaxf(m, pl[j]);
        float e[16];
        float s = 0.f;
#pragma unroll
        for (int j = 0; j < 16; ++j) { e[j] = expf(pl[j] - m); s += e[j]; }
        const float inv = 1.0f / s;
        float* po = attn_out + (row0 + r) * 128 + h * 16;
#pragma unroll
        for (int j = 0; j < 16; ++j) po[j] = e[j] * inv;
    }
}

// ---------------------------------------------------------------- K2: v proj
// v = value @ Wv + bv, stored bf16. 16 rows/block, 256 threads (1 col each).
__global__ __launch_bounds__(256) void k_vproj(
    const float* __restrict__ value, const float* __restrict__ Wv,
    const float* __restrict__ bv, __hip_bfloat16* __restrict__ v_out)
{
    __shared__ float sv[16 * 256];
    const int t = threadIdx.x;
    const int row0 = blockIdx.x * 16;
    const float4* src = (const float4*)(value + (long)row0 * 256);
#pragma unroll
    for (int i = 0; i < 4; ++i) ((float4*)sv)[t + i * 256] = src[t + i * 256];
    __syncthreads();

    float acc[16];
#pragma unroll
    for (int r = 0; r < 16; ++r) acc[r] = 0.f;
    const float* wp = Wv + t;
    for (int kq = 0; kq < 64; ++kq) {
        const float w0 = wp[(kq * 4 + 0) * 256];
        const float w1 = wp[(kq * 4 + 1) * 256];
        const float w2 = wp[(kq * 4 + 2) * 256];
        const float w3 = wp[(kq * 4 + 3) * 256];
#pragma unroll
        for (int r = 0; r < 16; ++r) {
            const float4 a = ((const float4*)(sv + r * 256))[kq];
            acc[r] = fmaf(a.x, w0, fmaf(a.y, w1, fmaf(a.z, w2, fmaf(a.w, w3, acc[r]))));
        }
    }
    const float b = bv[t];
#pragma unroll
    for (int r = 0; r < 16; ++r)
        v_out[(long)(row0 + r) * 256 + t] = __float2bfloat16(acc[r] + b);
}

// ---------------------------------------------------------------- K3: sample
// One block per (b,q); 256 threads = 8 heads x 32 dh.
__global__ __launch_bounds__(256) void k_sample(
    const float* __restrict__ refp, const float* __restrict__ off,
    const float* __restrict__ attn, const __hip_bfloat16* __restrict__ v,
    float* __restrict__ out_mid)
{
    __shared__ float soff[256];
    __shared__ float satt[128];
    __shared__ float sref[8];
    const int t = threadIdx.x;
    const int bq = blockIdx.x;
    const int b = bq / NQ_;
    soff[t] = off[bq * 256 + t];
    if (t < 128) satt[t] = attn[bq * 128 + t];
    if (t < 8)   sref[t] = refp[bq * 8 + t];
    __syncthreads();

    const int h = t >> 5, d = t & 31;
    const __hip_bfloat16* vb = v + (long)b * NV_ * 256 + h * 32 + d;
    float acc = 0.f;

    constexpr int HS[4] = {92, 46, 23, 12};
    constexpr int WS_[4] = {160, 80, 40, 20};
    constexpr int ST[4] = {0, 14720, 18400, 19320};
#pragma unroll
    for (int l = 0; l < 4; ++l) {
        const int Hl = HS[l], Wl = WS_[l], st = ST[l];
        const float rx = sref[l * 2 + 0], ry = sref[l * 2 + 1];
#pragma unroll
        for (int p = 0; p < 4; ++p) {
            const int c = h * 32 + l * 8 + p * 2;
            // x = refx*Wl + ox - 0.5 ; y = refy*Hl + oy - 0.5
            const float x = fmaf(rx, (float)Wl, soff[c])     - 0.5f;
            const float y = fmaf(ry, (float)Hl, soff[c + 1]) - 0.5f;
            const float aw = satt[h * 16 + l * 4 + p];
            const float x0f = floorf(x), y0f = floorf(y);
            const int x0 = (int)x0f, y0 = (int)y0f;
            const float wx1 = x - x0f, wx0 = 1.f - wx1;
            const float wy1 = y - y0f, wy0 = 1.f - wy1;
            const bool vx0 = (x0 >= 0) && (x0 < Wl);
            const bool vx1 = (x0 + 1 >= 0) && (x0 + 1 < Wl);
            if (y0 >= 0 && y0 < Hl) {
                const __hip_bfloat16* rowp = vb + (long)(st + y0 * Wl) * 256;
                if (vx0) acc += __bfloat162float(rowp[(long)x0 * 256])       * (wx0 * wy0 * aw);
                if (vx1) acc += __bfloat162float(rowp[(long)(x0 + 1) * 256]) * (wx1 * wy0 * aw);
            }
            if (y0 + 1 >= 0 && y0 + 1 < Hl) {
                const __hip_bfloat16* rowp = vb + (long)(st + (y0 + 1) * Wl) * 256;
                if (vx0) acc += __bfloat162float(rowp[(long)x0 * 256])       * (wx0 * wy1 * aw);
                if (vx1) acc += __bfloat162float(rowp[(long)(x0 + 1) * 256]) * (wx1 * wy1 * aw);
            }
        }
    }
    out_mid[bq * 256 + t] = acc;
}

// ---------------------------------------------------------------- K4: output
// out = mid @ Wo + bo + query. 16 rows/block, 256 threads.
__global__ __launch_bounds__(256) void k_out(
    const float* __restrict__ mid, const float* __restrict__ Wo,
    const float* __restrict__ bo, const float* __restrict__ query,
    float* __restrict__ out)
{
    __shared__ float sv[16 * 256];
    const int t = threadIdx.x;
    const int row0 = blockIdx.x * 16;
    const float4* src = (const float4*)(mid + row0 * 256);
#pragma unroll
    for (int i = 0; i < 4; ++i) ((float4*)sv)[t + i * 256] = src[t + i * 256];
    __syncthreads();

    float acc[16];
#pragma unroll
    for (int r = 0; r < 16; ++r) acc[r] = 0.f;
    const float* wp = Wo + t;
    for (int kq = 0; kq < 64; ++kq) {
        const float w0 = wp[(kq * 4 + 0) * 256];
        const float w1 = wp[(kq * 4 + 1) * 256];
        const float w2 = wp[(kq * 4 + 2) * 256];
        const float w3 = wp[(kq * 4 + 3) * 256];
#pragma unroll
        for (int r = 0; r < 16; ++r) {
            const float4 a = ((const float4*)(sv + r * 256))[kq];
            acc[r] = fmaf(a.x, w0, fmaf(a.y, w1, fmaf(a.z, w2, fmaf(a.w, w3, acc[r]))));
        }
    }
    const float b = bo[t];
#pragma unroll
    for (int r = 0; r < 16; ++r) {
        const int row = row0 + r;
        out[row * 256 + t] = acc[r] + b + query[row * 256 + t];
    }
}

// ---------------------------------------------------------------- launch
extern "C" void kernel_launch(void* const* d_in, const int* in_sizes, int n_in,
                              void* d_out, int out_size, void* d_ws, size_t ws_size,
                              hipStream_t stream)
{
    const float* query = (const float*)d_in[0];
    const float* value = (const float*)d_in[1];
    const float* refp  = (const float*)d_in[2];
    const float* Wv    = (const float*)d_in[3];
    const float* bv    = (const float*)d_in[4];
    const float* Ws    = (const float*)d_in[5];
    const float* bs    = (const float*)d_in[6];
    const float* Wa    = (const float*)d_in[7];
    const float* ba    = (const float*)d_in[8];
    const float* Wo    = (const float*)d_in[9];
    const float* bo    = (const float*)d_in[10];
    float* out = (float*)d_out;

    char* ws = (char*)d_ws;
    // layout: v(bf16) | off(f32) | attn(f32) | mid(f32)
    __hip_bfloat16* v_ws = (__hip_bfloat16*)ws;                            // 80,117,760 B
    float* off_ws  = (float*)(ws + 80117760);                              //  7,372,800 B
    float* attn_ws = (float*)(ws + 80117760 + 7372800);                    //  3,686,400 B
    float* mid_ws  = (float*)(ws + 80117760 + 7372800 + 3686400);          //  7,372,800 B

    k_params<<<dim3(B_ * NQ_ / 4), dim3(128), 0, stream>>>(query, Ws, bs, Wa, ba, off_ws, attn_ws);
    k_vproj <<<dim3(B_ * NV_ / 16), dim3(256), 0, stream>>>(value, Wv, bv, v_ws);
    k_sample<<<dim3(B_ * NQ_), dim3(256), 0, stream>>>(refp, off_ws, attn_ws, v_ws, mid_ws);
    k_out   <<<dim3(B_ * NQ_ / 16), dim3(256), 0, stream>>>(mid_ws, Wo, bo, query, out);
}

// Round 2
// 265.083 us; speedup vs baseline: 1.9908x; 1.9908x over previous
//
#include <hip/hip_runtime.h>
#include <hip/hip_bf16.h>

// Deformable attention (Deformable-DETR) on MI355X.
// Static problem: B=8, NQ=900, E=256, H=8, L=4, P=4, dh=32, NV=19560
// levels (h,w): (92,160) (46,80) (23,40) (12,20); starts 0,14720,18400,19320

#define B_   8
#define NQ_  900
#define E_   256
#define H_   8
#define NV_  19560
#define M_TOT (B_ * NV_)   // 156480 rows of value across batch

typedef __attribute__((ext_vector_type(8))) __bf16 bf16x8;
typedef __attribute__((ext_vector_type(4))) float f32x4;

__device__ __forceinline__ unsigned short f2bf(float x) {
    unsigned int u = __builtin_bit_cast(unsigned int, x);
    u += 0x7FFFu + ((u >> 16) & 1u);          // RNE to bf16
    return (unsigned short)(u >> 16);
}

// ---------------------------------------------------------------- K1: params
// off = query@Ws + bs  (256 cols), logits = query@Wa + ba (128 cols),
// softmax over each h's 16 logits. 4 query rows per block, 128 threads.
__global__ __launch_bounds__(128) void k_params(
    const float* __restrict__ query, const float* __restrict__ Ws,
    const float* __restrict__ bs, const float* __restrict__ Wa,
    const float* __restrict__ ba, float* __restrict__ off_out,
    float* __restrict__ attn_out)
{
    __shared__ float sq[4 * 256];
    __shared__ float slog[4 * 128];
    const int t = threadIdx.x;
    const int row0 = blockIdx.x * 4;      // flat (b*NQ+q) base
    const float4* qsrc = (const float4*)(query + row0 * 256);
    for (int i = t; i < 256; i += 128) ((float4*)sq)[i] = qsrc[i];
    __syncthreads();

    float a0[4] = {0,0,0,0}, a1[4] = {0,0,0,0}, a2[4] = {0,0,0,0};
    for (int k = 0; k < 256; ++k) {
        const float w0 = Ws[k * 256 + t];
        const float w1 = Ws[k * 256 + t + 128];
        const float w2 = Wa[k * 128 + t];
#pragma unroll
        for (int r = 0; r < 4; ++r) {
            const float q = sq[r * 256 + k];
            a0[r] = fmaf(q, w0, a0[r]);
            a1[r] = fmaf(q, w1, a1[r]);
            a2[r] = fmaf(q, w2, a2[r]);
        }
    }
    const float b0 = bs[t], b1 = bs[t + 128], b2 = ba[t];
#pragma unroll
    for (int r = 0; r < 4; ++r) {
        off_out[(row0 + r) * 256 + t]       = a0[r] + b0;
        off_out[(row0 + r) * 256 + t + 128] = a1[r] + b1;
        slog[r * 128 + t]                   = a2[r] + b2;
    }
    __syncthreads();
    if (t < 32) {                         // 4 rows x 8 heads
        const int r = t >> 3, h = t & 7;
        const float* pl = slog + r * 128 + h * 16;
        float m = pl[0];
#pragma unroll
        for (int j = 1; j < 16; ++j) m = fmaxf(m, pl[j]);
        float e[16];
        float s = 0.f;
#pragma unroll
        for (int j = 0; j < 16; ++j) { e[j] = expf(pl[j] - m); s += e[j]; }
        const float inv = 1.0f / s;
        float* po = attn_out + (row0 + r) * 128 + h * 16;
#pragma unroll
        for (int j = 0; j < 16; ++j) po[j] = e[j] * inv;
    }
}

// ---------------------------------------------------------------- K2a: Wv prep
// WvT bf16, pre-swizzled "LDS image" so k_vgemm can global_load_lds linearly.
// img[ks][col][rr] (ks=K-step of 128, col=0..255, rr=0..127):
//   img[...] = bf16( Wv[ ks*128 + (rr ^ ((col&7)<<3)) ][ col ] )
__global__ __launch_bounds__(256) void k_wvprep(
    const float* __restrict__ Wv, unsigned short* __restrict__ img)
{
    const int i = blockIdx.x * 256 + threadIdx.x;   // 0..65535
    const int ks  = i >> 15;
    const int col = (i >> 7) & 255;
    const int rr  = i & 127;
    const int k   = ks * 128 + (rr ^ ((col & 7) << 3));
    img[i] = f2bf(Wv[k * 256 + col]);
}

// ---------------------------------------------------------------- K2b: v proj (MFMA)
// v = value @ Wv + bv, stored bf16. Tile BM=128 x BN=256(full), BK=128 x 2.
// 512 threads = 8 waves (2x4), each wave owns a 64x64 output sub-tile.
// LDS: sA[128][128] bf16 (XOR-swizzled) | sB[256][128] bf16 (pre-swizzled img).
__global__ __launch_bounds__(512) void k_vgemm(
    const float* __restrict__ value, const unsigned short* __restrict__ wvt,
    const float* __restrict__ bv, unsigned short* __restrict__ v_out)
{
    extern __shared__ unsigned short sm[];
    unsigned short* sA = sm;               // 128*128 = 16384 u16 (32 KB)
    unsigned short* sB = sm + 128 * 128;   // 256*128 = 32768 u16 (64 KB)

    const int t = threadIdx.x;
    const int w = t >> 6, l = t & 63;
    const int wr = w >> 2, wc = w & 3;           // wave grid 2 x 4
    const int row0 = blockIdx.x * 128;

    f32x4 acc[4][4];
#pragma unroll
    for (int m = 0; m < 4; ++m)
#pragma unroll
        for (int n = 0; n < 4; ++n) acc[m][n] = (f32x4){0.f, 0.f, 0.f, 0.f};

    for (int ks = 0; ks < 2; ++ks) {
        // --- B: linear async copy of the pre-swizzled image (8 x 8KB) ---
        const unsigned short* bsrc = wvt + ks * 32768 + t * 8;
#pragma unroll
        for (int i = 0; i < 8; ++i) {
            __builtin_amdgcn_global_load_lds(
                (const __attribute__((address_space(1))) unsigned int*)(bsrc + i * 4096),
                (__attribute__((address_space(3))) unsigned int*)(sB + i * 4096 + t * 8),
                16, 0, 0);
        }
        // --- A: reg-stage fp32 -> bf16, swizzled ds_write_b64 ---
#pragma unroll
        for (int i = 0; i < 8; ++i) {
            const int idx = i * 512 + t;
            const int row = idx >> 5, kq = idx & 31;   // kq = float4 index in K
            const int grow = row0 + row;
            f32x4 v4 = (f32x4){0.f, 0.f, 0.f, 0.f};
            if (grow < M_TOT)
                v4 = *(const f32x4*)(value + (long)grow * 256 + ks * 128 + kq * 4);
            unsigned short* dst = sA + row * 128 + ((kq * 4) ^ ((row & 7) << 3));
            const unsigned int p0 = (unsigned)f2bf(v4.x) | ((unsigned)f2bf(v4.y) << 16);
            const unsigned int p1 = (unsigned)f2bf(v4.z) | ((unsigned)f2bf(v4.w) << 16);
            *(uint2*)dst = make_uint2(p0, p1);
        }
        __syncthreads();   // drains vmcnt (global_load_lds) + lgkm

        // --- compute: 4 k-chunks of 32, 16 MFMA each per wave ---
#pragma unroll
        for (int kk = 0; kk < 4; ++kk) {
            const int kb = kk * 32 + (l >> 4) * 8;
            bf16x8 af[4], bfr[4];
#pragma unroll
            for (int m = 0; m < 4; ++m) {
                const int row = wr * 64 + m * 16 + (l & 15);
                af[m] = *(const bf16x8*)(sA + row * 128 + (kb ^ ((row & 7) << 3)));
            }
#pragma unroll
            for (int n = 0; n < 4; ++n) {
                const int col = wc * 64 + n * 16 + (l & 15);
                bfr[n] = *(const bf16x8*)(sB + col * 128 + (kb ^ ((col & 7) << 3)));
            }
#pragma unroll
            for (int m = 0; m < 4; ++m)
#pragma unroll
                for (int n = 0; n < 4; ++n)
                    acc[m][n] = __builtin_amdgcn_mfma_f32_16x16x32_bf16(
                        af[m], bfr[n], acc[m][n], 0, 0, 0);
        }
        __syncthreads();
    }

    // --- epilogue: +bias, bf16 store. C map: col=l&15, row=(l>>4)*4+j ---
#pragma unroll
    for (int n = 0; n < 4; ++n) {
        const int col = wc * 64 + n * 16 + (l & 15);
        const float bb = bv[col];
#pragma unroll
        for (int m = 0; m < 4; ++m) {
            const int rbase = row0 + wr * 64 + m * 16 + (l >> 4) * 4;
#pragma unroll
            for (int j = 0; j < 4; ++j) {
                const int row = rbase + j;
                if (row < M_TOT)
                    v_out[(long)row * 256 + col] = f2bf(acc[m][n][j] + bb);
            }
        }
    }
}

// ---------------------------------------------------------------- K3: sample
// One block per (b,q); 256 threads = 8 heads x 32 dh.
__global__ __launch_bounds__(256) void k_sample(
    const float* __restrict__ refp, const float* __restrict__ off,
    const float* __restrict__ attn, const __hip_bfloat16* __restrict__ v,
    float* __restrict__ out_mid)
{
    __shared__ float soff[256];
    __shared__ float satt[128];
    __shared__ float sref[8];
    const int t = threadIdx.x;
    const int bq = blockIdx.x;
    const int b = bq / NQ_;
    soff[t] = off[bq * 256 + t];
    if (t < 128) satt[t] = attn[bq * 128 + t];
    if (t < 8)   sref[t] = refp[bq * 8 + t];
    __syncthreads();

    const int h = t >> 5, d = t & 31;
    const __hip_bfloat16* vb = v + (long)b * NV_ * 256 + h * 32 + d;
    float acc = 0.f;

    constexpr int HS[4] = {92, 46, 23, 12};
    constexpr int WS_[4] = {160, 80, 40, 20};
    constexpr int ST[4] = {0, 14720, 18400, 19320};
#pragma unroll
    for (int l = 0; l < 4; ++l) {
        const int Hl = HS[l], Wl = WS_[l], st = ST[l];
        const float rx = sref[l * 2 + 0], ry = sref[l * 2 + 1];
#pragma unroll
        for (int p = 0; p < 4; ++p) {
            const int c = h * 32 + l * 8 + p * 2;
            const float x = fmaf(rx, (float)Wl, soff[c])     - 0.5f;
            const float y = fmaf(ry, (float)Hl, soff[c + 1]) - 0.5f;
            const float aw = satt[h * 16 + l * 4 + p];
            const float x0f = floorf(x), y0f = floorf(y);
            const int x0 = (int)x0f, y0 = (int)y0f;
            const float wx1 = x - x0f, wx0 = 1.f - wx1;
            const float wy1 = y - y0f, wy0 = 1.f - wy1;
            const bool vx0 = (x0 >= 0) && (x0 < Wl);
            const bool vx1 = (x0 + 1 >= 0) && (x0 + 1 < Wl);
            if (y0 >= 0 && y0 < Hl) {
                const __hip_bfloat16* rowp = vb + (long)(st + y0 * Wl) * 256;
                if (vx0) acc += __bfloat162float(rowp[(long)x0 * 256])       * (wx0 * wy0 * aw);
                if (vx1) acc += __bfloat162float(rowp[(long)(x0 + 1) * 256]) * (wx1 * wy0 * aw);
            }
            if (y0 + 1 >= 0 && y0 + 1 < Hl) {
                const __hip_bfloat16* rowp = vb + (long)(st + (y0 + 1) * Wl) * 256;
                if (vx0) acc += __bfloat162float(rowp[(long)x0 * 256])       * (wx0 * wy1 * aw);
                if (vx1) acc += __bfloat162float(rowp[(long)(x0 + 1) * 256]) * (wx1 * wy1 * aw);
            }
        }
    }
    out_mid[bq * 256 + t] = acc;
}

// ---------------------------------------------------------------- K4: output
// out = mid @ Wo + bo + query. 16 rows/block, 256 threads.
__global__ __launch_bounds__(256) void k_out(
    const float* __restrict__ mid, const float* __restrict__ Wo,
    const float* __restrict__ bo, const float* __restrict__ query,
    float* __restrict__ out)
{
    __shared__ float sv[16 * 256];
    const int t = threadIdx.x;
    const int row0 = blockIdx.x * 16;
    const float4* src = (const float4*)(mid + row0 * 256);
#pragma unroll
    for (int i = 0; i < 4; ++i) ((float4*)sv)[t + i * 256] = src[t + i * 256];
    __syncthreads();

    float acc[16];
#pragma unroll
    for (int r = 0; r < 16; ++r) acc[r] = 0.f;
    const float* wp = Wo + t;
    for (int kq = 0; kq < 64; ++kq) {
        const float w0 = wp[(kq * 4 + 0) * 256];
        const float w1 = wp[(kq * 4 + 1) * 256];
        const float w2 = wp[(kq * 4 + 2) * 256];
        const float w3 = wp[(kq * 4 + 3) * 256];
#pragma unroll
        for (int r = 0; r < 16; ++r) {
            const float4 a = ((const float4*)(sv + r * 256))[kq];
            acc[r] = fmaf(a.x, w0, fmaf(a.y, w1, fmaf(a.z, w2, fmaf(a.w, w3, acc[r]))));
        }
    }
    const float b = bo[t];
#pragma unroll
    for (int r = 0; r < 16; ++r) {
        const int row = row0 + r;
        out[row * 256 + t] = acc[r] + b + query[row * 256 + t];
    }
}

// ---------------------------------------------------------------- launch
extern "C" void kernel_launch(void* const* d_in, const int* in_sizes, int n_in,
                              void* d_out, int out_size, void* d_ws, size_t ws_size,
                              hipStream_t stream)
{
    const float* query = (const float*)d_in[0];
    const float* value = (const float*)d_in[1];
    const float* refp  = (const float*)d_in[2];
    const float* Wv    = (const float*)d_in[3];
    const float* bv    = (const float*)d_in[4];
    const float* Ws    = (const float*)d_in[5];
    const float* bs    = (const float*)d_in[6];
    const float* Wa    = (const float*)d_in[7];
    const float* ba    = (const float*)d_in[8];
    const float* Wo    = (const float*)d_in[9];
    const float* bo    = (const float*)d_in[10];
    float* out = (float*)d_out;

    char* ws = (char*)d_ws;
    // layout: v(bf16) | off(f32) | attn(f32) | mid(f32) | wvt(bf16 img)
    unsigned short* v_ws = (unsigned short*)ws;                            // 80,117,760 B
    float* off_ws  = (float*)(ws + 80117760);                              //  7,372,800 B
    float* attn_ws = (float*)(ws + 80117760 + 7372800);                    //  3,686,400 B
    float* mid_ws  = (float*)(ws + 80117760 + 7372800 + 3686400);          //  7,372,800 B
    unsigned short* wvt_ws = (unsigned short*)(ws + 80117760 + 7372800 + 3686400 + 7372800); // 131,072 B

    k_wvprep<<<dim3(256), dim3(256), 0, stream>>>(Wv, wvt_ws);
    k_params<<<dim3(B_ * NQ_ / 4), dim3(128), 0, stream>>>(query, Ws, bs, Wa, ba, off_ws, attn_ws);
    k_vgemm <<<dim3((M_TOT + 127) / 128), dim3(512), 98304, stream>>>(value, wvt_ws, bv, v_ws);
    k_sample<<<dim3(B_ * NQ_), dim3(256), 0, stream>>>(refp, off_ws, attn_ws,
                                                       (const __hip_bfloat16*)v_ws, mid_ws);
    k_out   <<<dim3(B_ * NQ_ / 16), dim3(256), 0, stream>>>(mid_ws, Wo, bo, query, out);
}

// Round 3
// 229.418 us; speedup vs baseline: 2.3003x; 1.1555x over previous
//
#include <hip/hip_runtime.h>
#include <hip/hip_bf16.h>

// Deformable attention (Deformable-DETR) on MI355X.
// Static problem: B=8, NQ=900, E=256, H=8, L=4, P=4, dh=32, NV=19560
// levels (h,w): (92,160) (46,80) (23,40) (12,20); starts 0,14720,18400,19320

#define B_   8
#define NQ_  900
#define E_   256
#define H_   8
#define NV_  19560
#define M_TOT (B_ * NV_)   // 156480 rows of value across batch

typedef __attribute__((ext_vector_type(8))) __bf16 bf16x8;
typedef __attribute__((ext_vector_type(4))) float f32x4;

__device__ __forceinline__ unsigned short f2bf(float x) {
    unsigned int u = __builtin_bit_cast(unsigned int, x);
    u += 0x7FFFu + ((u >> 16) & 1u);          // RNE to bf16
    return (unsigned short)(u >> 16);
}

// ---------------------------------------------------------------- K1: params
// off = query@Ws + bs  (256 cols), logits = query@Wa + ba (128 cols),
// softmax over each h's 16 logits. 4 query rows per block, 128 threads.
__global__ __launch_bounds__(128) void k_params(
    const float* __restrict__ query, const float* __restrict__ Ws,
    const float* __restrict__ bs, const float* __restrict__ Wa,
    const float* __restrict__ ba, float* __restrict__ off_out,
    float* __restrict__ attn_out)
{
    __shared__ float sq[4 * 256];
    __shared__ float slog[4 * 128];
    const int t = threadIdx.x;
    const int row0 = blockIdx.x * 4;      // flat (b*NQ+q) base
    const float4* qsrc = (const float4*)(query + row0 * 256);
    for (int i = t; i < 256; i += 128) ((float4*)sq)[i] = qsrc[i];
    __syncthreads();

    float a0[4] = {0,0,0,0}, a1[4] = {0,0,0,0}, a2[4] = {0,0,0,0};
    for (int k = 0; k < 256; ++k) {
        const float w0 = Ws[k * 256 + t];
        const float w1 = Ws[k * 256 + t + 128];
        const float w2 = Wa[k * 128 + t];
#pragma unroll
        for (int r = 0; r < 4; ++r) {
            const float q = sq[r * 256 + k];
            a0[r] = fmaf(q, w0, a0[r]);
            a1[r] = fmaf(q, w1, a1[r]);
            a2[r] = fmaf(q, w2, a2[r]);
        }
    }
    const float b0 = bs[t], b1 = bs[t + 128], b2 = ba[t];
#pragma unroll
    for (int r = 0; r < 4; ++r) {
        off_out[(row0 + r) * 256 + t]       = a0[r] + b0;
        off_out[(row0 + r) * 256 + t + 128] = a1[r] + b1;
        slog[r * 128 + t]                   = a2[r] + b2;
    }
    __syncthreads();
    if (t < 32) {                         // 4 rows x 8 heads
        const int r = t >> 3, h = t & 7;
        const float* pl = slog + r * 128 + h * 16;
        float m = pl[0];
#pragma unroll
        for (int j = 1; j < 16; ++j) m = fmaxf(m, pl[j]);
        float e[16];
        float s = 0.f;
#pragma unroll
        for (int j = 0; j < 16; ++j) { e[j] = expf(pl[j] - m); s += e[j]; }
        const float inv = 1.0f / s;
        float* po = attn_out + (row0 + r) * 128 + h * 16;
#pragma unroll
        for (int j = 0; j < 16; ++j) po[j] = e[j] * inv;
    }
}

// ---------------------------------------------------------------- K2a: Wv prep
// WvT bf16, pre-swizzled "LDS image" for BK=64 K-steps:
// img[ks(4)][col(256)][rr(64)] = bf16( Wv[ ks*64 + (rr ^ ((col&7)<<3)) ][ col ] )
__global__ __launch_bounds__(256) void k_wvprep(
    const float* __restrict__ Wv, unsigned short* __restrict__ img)
{
    const int i = blockIdx.x * 256 + threadIdx.x;   // 0..65535
    const int ks  = i >> 14;
    const int col = (i >> 6) & 255;
    const int rr  = i & 63;
    const int k   = ks * 64 + (rr ^ ((col & 7) << 3));
    img[i] = f2bf(Wv[k * 256 + col]);
}

// ---------------------------------------------------------------- K2b: v proj (MFMA)
// v = value @ Wv + bv, stored bf16. Tile BM=128 x BN=256(full), BK=64 x 4.
// 512 threads = 8 waves (2x4), each wave owns a 64x64 output sub-tile.
// LDS 48KB single-buffered -> 3 blocks/CU (the occupancy lever vs R1's 96KB).
// Epilogue stores through LDS for full-line coalesced uint4 writes.
__global__ __launch_bounds__(512) void k_vgemm(
    const float* __restrict__ value, const unsigned short* __restrict__ wvt,
    const float* __restrict__ bv, unsigned short* __restrict__ v_out)
{
    __shared__ unsigned short sm[24576];   // 48 KB
    unsigned short* sA = sm;               // 128*64 u16 (16 KB), XOR-swizzled
    unsigned short* sB = sm + 128 * 64;    // 256*64 u16 (32 KB), pre-swizzled img

    const int t = threadIdx.x;
    const int w = t >> 6, l = t & 63;
    const int wr = w >> 2, wc = w & 3;           // wave grid 2 x 4
    const int row0 = blockIdx.x * 128;

    f32x4 acc[4][4];
#pragma unroll
    for (int m = 0; m < 4; ++m)
#pragma unroll
        for (int n = 0; n < 4; ++n) acc[m][n] = (f32x4){0.f, 0.f, 0.f, 0.f};

    for (int ks = 0; ks < 4; ++ks) {
        // --- B: linear async copy of the pre-swizzled image (4 x 8KB) ---
        const unsigned short* bsrc = wvt + ks * 16384 + t * 8;
#pragma unroll
        for (int i = 0; i < 4; ++i) {
            __builtin_amdgcn_global_load_lds(
                (const __attribute__((address_space(1))) unsigned int*)(bsrc + i * 4096),
                (__attribute__((address_space(3))) unsigned int*)(sB + i * 4096 + t * 8),
                16, 0, 0);
        }
        // --- A: reg-stage fp32 -> bf16, swizzled 8B ds_write ---
#pragma unroll
        for (int i = 0; i < 4; ++i) {
            const int idx = i * 512 + t;
            const int row = idx >> 4, kq = idx & 15;   // kq = float4 index in K-step
            const int grow = row0 + row;
            f32x4 v4 = (f32x4){0.f, 0.f, 0.f, 0.f};
            if (grow < M_TOT)
                v4 = *(const f32x4*)(value + (long)grow * 256 + ks * 64 + kq * 4);
            unsigned short* dst = sA + row * 64 + ((kq * 4) ^ ((row & 7) << 3));
            const unsigned int p0 = (unsigned)f2bf(v4.x) | ((unsigned)f2bf(v4.y) << 16);
            const unsigned int p1 = (unsigned)f2bf(v4.z) | ((unsigned)f2bf(v4.w) << 16);
            *(uint2*)dst = make_uint2(p0, p1);
        }
        __syncthreads();   // drains vmcnt (global_load_lds) + lgkm

        // --- compute: 2 k-chunks of 32, 16 MFMA each per wave ---
#pragma unroll
        for (int kk = 0; kk < 2; ++kk) {
            const int kb = kk * 32 + (l >> 4) * 8;
            bf16x8 af[4], bfr[4];
#pragma unroll
            for (int m = 0; m < 4; ++m) {
                const int row = wr * 64 + m * 16 + (l & 15);
                af[m] = *(const bf16x8*)(sA + row * 64 + (kb ^ ((row & 7) << 3)));
            }
#pragma unroll
            for (int n = 0; n < 4; ++n) {
                const int col = wc * 64 + n * 16 + (l & 15);
                bfr[n] = *(const bf16x8*)(sB + col * 64 + (kb ^ ((col & 7) << 3)));
            }
#pragma unroll
            for (int m = 0; m < 4; ++m)
#pragma unroll
                for (int n = 0; n < 4; ++n)
                    acc[m][n] = __builtin_amdgcn_mfma_f32_16x16x32_bf16(
                        af[m], bfr[n], acc[m][n], 0, 0, 0);
        }
        __syncthreads();
    }

    // --- epilogue: +bias -> LDS (bf16) -> coalesced uint4 stores ---
    float bb[4];
#pragma unroll
    for (int n = 0; n < 4; ++n) bb[n] = bv[wc * 64 + n * 16 + (l & 15)];

#pragma unroll
    for (int c = 0; c < 2; ++c) {          // 64-row chunks (32 KB in sm)
        if (wr == c) {
#pragma unroll
            for (int m = 0; m < 4; ++m) {
                const int lr0 = m * 16 + (l >> 4) * 4;
#pragma unroll
                for (int n = 0; n < 4; ++n) {
                    const int col = wc * 64 + n * 16 + (l & 15);
#pragma unroll
                    for (int j = 0; j < 4; ++j)
                        sm[(lr0 + j) * 256 + col] = f2bf(acc[m][n][j] + bb[n]);
                }
            }
        }
        __syncthreads();
#pragma unroll
        for (int i = 0; i < 4; ++i) {
            const int lidx = i * 512 + t;              // 0..2047 (16B units)
            const int grow = row0 + c * 64 + (lidx >> 5);
            if (grow < M_TOT)
                *(uint4*)(v_out + (long)grow * 256 + (lidx & 31) * 8) =
                    *(const uint4*)(sm + lidx * 8);
        }
        __syncthreads();
    }
}

// ---------------------------------------------------------------- K3: sample
// One block per (b,q); 256 threads = 8 heads x 32 dh.
__global__ __launch_bounds__(256) void k_sample(
    const float* __restrict__ refp, const float* __restrict__ off,
    const float* __restrict__ attn, const __hip_bfloat16* __restrict__ v,
    float* __restrict__ out_mid)
{
    __shared__ float soff[256];
    __shared__ float satt[128];
    __shared__ float sref[8];
    const int t = threadIdx.x;
    const int bq = blockIdx.x;
    const int b = bq / NQ_;
    soff[t] = off[bq * 256 + t];
    if (t < 128) satt[t] = attn[bq * 128 + t];
    if (t < 8)   sref[t] = refp[bq * 8 + t];
    __syncthreads();

    const int h = t >> 5, d = t & 31;
    const __hip_bfloat16* vb = v + (long)b * NV_ * 256 + h * 32 + d;
    float acc = 0.f;

    constexpr int HS[4] = {92, 46, 23, 12};
    constexpr int WS_[4] = {160, 80, 40, 20};
    constexpr int ST[4] = {0, 14720, 18400, 19320};
#pragma unroll
    for (int l = 0; l < 4; ++l) {
        const int Hl = HS[l], Wl = WS_[l], st = ST[l];
        const float rx = sref[l * 2 + 0], ry = sref[l * 2 + 1];
#pragma unroll
        for (int p = 0; p < 4; ++p) {
            const int c = h * 32 + l * 8 + p * 2;
            const float x = fmaf(rx, (float)Wl, soff[c])     - 0.5f;
            const float y = fmaf(ry, (float)Hl, soff[c + 1]) - 0.5f;
            const float aw = satt[h * 16 + l * 4 + p];
            const float x0f = floorf(x), y0f = floorf(y);
            const int x0 = (int)x0f, y0 = (int)y0f;
            const float wx1 = x - x0f, wx0 = 1.f - wx1;
            const float wy1 = y - y0f, wy0 = 1.f - wy1;
            const bool vx0 = (x0 >= 0) && (x0 < Wl);
            const bool vx1 = (x0 + 1 >= 0) && (x0 + 1 < Wl);
            if (y0 >= 0 && y0 < Hl) {
                const __hip_bfloat16* rowp = vb + (long)(st + y0 * Wl) * 256;
                if (vx0) acc += __bfloat162float(rowp[(long)x0 * 256])       * (wx0 * wy0 * aw);
                if (vx1) acc += __bfloat162float(rowp[(long)(x0 + 1) * 256]) * (wx1 * wy0 * aw);
            }
            if (y0 + 1 >= 0 && y0 + 1 < Hl) {
                const __hip_bfloat16* rowp = vb + (long)(st + (y0 + 1) * Wl) * 256;
                if (vx0) acc += __bfloat162float(rowp[(long)x0 * 256])       * (wx0 * wy1 * aw);
                if (vx1) acc += __bfloat162float(rowp[(long)(x0 + 1) * 256]) * (wx1 * wy1 * aw);
            }
        }
    }
    out_mid[bq * 256 + t] = acc;
}

// ---------------------------------------------------------------- K4: output
// out = mid @ Wo + bo + query. 16 rows/block, 256 threads.
__global__ __launch_bounds__(256) void k_out(
    const float* __restrict__ mid, const float* __restrict__ Wo,
    const float* __restrict__ bo, const float* __restrict__ query,
    float* __restrict__ out)
{
    __shared__ float sv[16 * 256];
    const int t = threadIdx.x;
    const int row0 = blockIdx.x * 16;
    const float4* src = (const float4*)(mid + row0 * 256);
#pragma unroll
    for (int i = 0; i < 4; ++i) ((float4*)sv)[t + i * 256] = src[t + i * 256];
    __syncthreads();

    float acc[16];
#pragma unroll
    for (int r = 0; r < 16; ++r) acc[r] = 0.f;
    const float* wp = Wo + t;
    for (int kq = 0; kq < 64; ++kq) {
        const float w0 = wp[(kq * 4 + 0) * 256];
        const float w1 = wp[(kq * 4 + 1) * 256];
        const float w2 = wp[(kq * 4 + 2) * 256];
        const float w3 = wp[(kq * 4 + 3) * 256];
#pragma unroll
        for (int r = 0; r < 16; ++r) {
            const float4 a = ((const float4*)(sv + r * 256))[kq];
            acc[r] = fmaf(a.x, w0, fmaf(a.y, w1, fmaf(a.z, w2, fmaf(a.w, w3, acc[r]))));
        }
    }
    const float b = bo[t];
#pragma unroll
    for (int r = 0; r < 16; ++r) {
        const int row = row0 + r;
        out[row * 256 + t] = acc[r] + b + query[row * 256 + t];
    }
}

// ---------------------------------------------------------------- launch
extern "C" void kernel_launch(void* const* d_in, const int* in_sizes, int n_in,
                              void* d_out, int out_size, void* d_ws, size_t ws_size,
                              hipStream_t stream)
{
    const float* query = (const float*)d_in[0];
    const float* value = (const float*)d_in[1];
    const float* refp  = (const float*)d_in[2];
    const float* Wv    = (const float*)d_in[3];
    const float* bv    = (const float*)d_in[4];
    const float* Ws    = (const float*)d_in[5];
    const float* bs    = (const float*)d_in[6];
    const float* Wa    = (const float*)d_in[7];
    const float* ba    = (const float*)d_in[8];
    const float* Wo    = (const float*)d_in[9];
    const float* bo    = (const float*)d_in[10];
    float* out = (float*)d_out;

    char* ws = (char*)d_ws;
    // layout: v(bf16) | off(f32) | attn(f32) | mid(f32) | wvt(bf16 img)
    unsigned short* v_ws = (unsigned short*)ws;                            // 80,117,760 B
    float* off_ws  = (float*)(ws + 80117760);                              //  7,372,800 B
    float* attn_ws = (float*)(ws + 80117760 + 7372800);                    //  3,686,400 B
    float* mid_ws  = (float*)(ws + 80117760 + 7372800 + 3686400);          //  7,372,800 B
    unsigned short* wvt_ws = (unsigned short*)(ws + 80117760 + 7372800 + 3686400 + 7372800); // 131,072 B

    k_wvprep<<<dim3(256), dim3(256), 0, stream>>>(Wv, wvt_ws);
    k_params<<<dim3(B_ * NQ_ / 4), dim3(128), 0, stream>>>(query, Ws, bs, Wa, ba, off_ws, attn_ws);
    k_vgemm <<<dim3((M_TOT + 127) / 128), dim3(512), 0, stream>>>(value, wvt_ws, bv, v_ws);
    k_sample<<<dim3(B_ * NQ_), dim3(256), 0, stream>>>(refp, off_ws, attn_ws,
                                                       (const __hip_bfloat16*)v_ws, mid_ws);
    k_out   <<<dim3(B_ * NQ_ / 16), dim3(256), 0, stream>>>(mid_ws, Wo, bo, query, out);
}

// Round 4
// 203.112 us; speedup vs baseline: 2.5982x; 1.1295x over previous
//
#include <hip/hip_runtime.h>
#include <hip/hip_bf16.h>

// Deformable attention (Deformable-DETR) on MI355X.
// Static problem: B=8, NQ=900, E=256, H=8, L=4, P=4, dh=32, NV=19560
// levels (h,w): (92,160) (46,80) (23,40) (12,20); starts 0,14720,18400,19320

#define B_   8
#define NQ_  900
#define E_   256
#define H_   8
#define NV_  19560
#define M_TOT (B_ * NV_)   // 156480 = 64 * 2445 exactly

typedef __attribute__((ext_vector_type(8))) __bf16 bf16x8;
typedef __attribute__((ext_vector_type(4))) float f32x4;

__device__ __forceinline__ unsigned short f2bf(float x) {
    unsigned int u = __builtin_bit_cast(unsigned int, x);
    u += 0x7FFFu + ((u >> 16) & 1u);          // RNE to bf16
    return (unsigned short)(u >> 16);
}

// ---------------------------------------------------------------- K1: params
// off = query@Ws + bs  (256 cols), logits = query@Wa + ba (128 cols),
// softmax over each h's 16 logits. 4 query rows per block, 128 threads.
__global__ __launch_bounds__(128) void k_params(
    const float* __restrict__ query, const float* __restrict__ Ws,
    const float* __restrict__ bs, const float* __restrict__ Wa,
    const float* __restrict__ ba, float* __restrict__ off_out,
    float* __restrict__ attn_out)
{
    __shared__ float sq[4 * 256];
    __shared__ float slog[4 * 128];
    const int t = threadIdx.x;
    const int row0 = blockIdx.x * 4;      // flat (b*NQ+q) base
    const float4* qsrc = (const float4*)(query + row0 * 256);
    for (int i = t; i < 256; i += 128) ((float4*)sq)[i] = qsrc[i];
    __syncthreads();

    float a0[4] = {0,0,0,0}, a1[4] = {0,0,0,0}, a2[4] = {0,0,0,0};
    for (int k = 0; k < 256; ++k) {
        const float w0 = Ws[k * 256 + t];
        const float w1 = Ws[k * 256 + t + 128];
        const float w2 = Wa[k * 128 + t];
#pragma unroll
        for (int r = 0; r < 4; ++r) {
            const float q = sq[r * 256 + k];
            a0[r] = fmaf(q, w0, a0[r]);
            a1[r] = fmaf(q, w1, a1[r]);
            a2[r] = fmaf(q, w2, a2[r]);
        }
    }
    const float b0 = bs[t], b1 = bs[t + 128], b2 = ba[t];
#pragma unroll
    for (int r = 0; r < 4; ++r) {
        off_out[(row0 + r) * 256 + t]       = a0[r] + b0;
        off_out[(row0 + r) * 256 + t + 128] = a1[r] + b1;
        slog[r * 128 + t]                   = a2[r] + b2;
    }
    __syncthreads();
    if (t < 32) {                         // 4 rows x 8 heads
        const int r = t >> 3, h = t & 7;
        const float* pl = slog + r * 128 + h * 16;
        float m = pl[0];
#pragma unroll
        for (int j = 1; j < 16; ++j) m = fmaxf(m, pl[j]);
        float e[16];
        float s = 0.f;
#pragma unroll
        for (int j = 0; j < 16; ++j) { e[j] = expf(pl[j] - m); s += e[j]; }
        const float inv = 1.0f / s;
        float* po = attn_out + (row0 + r) * 128 + h * 16;
#pragma unroll
        for (int j = 0; j < 16; ++j) po[j] = e[j] * inv;
    }
}

// ---------------------------------------------------------------- K2a: Wv prep
// WvT bf16, pre-swizzled "LDS image" for BK=64 K-steps:
// img[ks(4)][col(256)][rr(64)] = bf16( Wv[ ks*64 + (rr ^ ((col&7)<<3)) ][ col ] )
__global__ __launch_bounds__(256) void k_wvprep(
    const float* __restrict__ Wv, unsigned short* __restrict__ img)
{
    const int i = blockIdx.x * 256 + threadIdx.x;   // 0..65535
    const int ks  = i >> 14;
    const int col = (i >> 6) & 255;
    const int rr  = i & 63;
    const int k   = ks * 64 + (rr ^ ((col & 7) << 3));
    img[i] = f2bf(Wv[k * 256 + col]);
}

// ---------------------------------------------------------------- K2b: v proj (MFMA)
// v = value @ Wv + bv, stored bf16. Tile BM=64 x BN=256(full), BK=64 x 4.
// 256 threads = 4 waves, each wave owns a 64x64 output sub-tile.
// LDS 40KB -> 4 blocks/CU (16 waves, the VGPR-class max, in 4 INDEPENDENT
// barrier domains so stalls overlap across blocks). A prefetched to regs
// for the next K-step during compute (T14-lite).
__global__ __launch_bounds__(256) void k_vgemm(
    const float* __restrict__ value, const unsigned short* __restrict__ wvt,
    const float* __restrict__ bv, unsigned short* __restrict__ v_out)
{
    __shared__ unsigned short sm[20480];          // 40 KB
    unsigned short* sA = sm;                      // 64 rows x 64 k (8 KB, XOR-swz)
    unsigned short* sB = sm + 64 * 64;            // 256 cols x 64 k (32 KB, pre-swz)

    const int t = threadIdx.x;
    const int w = t >> 6, l = t & 63;             // wave 0..3 owns cols w*64..+63
    const int row0 = blockIdx.x * 64;

    f32x4 acc[4][4];
#pragma unroll
    for (int m = 0; m < 4; ++m)
#pragma unroll
        for (int n = 0; n < 4; ++n) acc[m][n] = (f32x4){0.f, 0.f, 0.f, 0.f};

    // A-stage geometry: per i, row = i*16 + (t>>4), kq = t&15 (float4 in K)
    const int tr = t >> 4, kq = t & 15;
    const int aswz = ((tr & 7) << 3);             // row&7 == tr&7 (i*16 = 0 mod 8)
    f32x4 areg[4];
#pragma unroll
    for (int i = 0; i < 4; ++i)
        areg[i] = *(const f32x4*)(value + (long)(row0 + i * 16 + tr) * 256 + kq * 4);

    for (int ks = 0; ks < 4; ++ks) {
        // --- A: regs -> bf16 -> swizzled 8B LDS write ---
#pragma unroll
        for (int i = 0; i < 4; ++i) {
            unsigned short* dst = sA + (i * 16 + tr) * 64 + ((kq * 4) ^ aswz);
            const unsigned int p0 = (unsigned)f2bf(areg[i].x) | ((unsigned)f2bf(areg[i].y) << 16);
            const unsigned int p1 = (unsigned)f2bf(areg[i].z) | ((unsigned)f2bf(areg[i].w) << 16);
            *(uint2*)dst = make_uint2(p0, p1);
        }
        // --- B: linear async copy of the pre-swizzled image (8 x 4KB) ---
        const unsigned short* bsrc = wvt + ks * 16384 + t * 8;
#pragma unroll
        for (int i = 0; i < 8; ++i) {
            __builtin_amdgcn_global_load_lds(
                (const __attribute__((address_space(1))) unsigned int*)(bsrc + i * 2048),
                (__attribute__((address_space(3))) unsigned int*)(sB + i * 2048 + t * 8),
                16, 0, 0);
        }
        __syncthreads();   // drains vmcnt (global_load_lds) + lgkm

        // --- prefetch next A tile into regs; overlaps with MFMA below ---
        if (ks < 3) {
#pragma unroll
            for (int i = 0; i < 4; ++i)
                areg[i] = *(const f32x4*)(value + (long)(row0 + i * 16 + tr) * 256
                                          + (ks + 1) * 64 + kq * 4);
        }

        // --- compute: 2 k-chunks of 32, 16 MFMA each per wave ---
        const int lswz = (l & 7) << 3;
#pragma unroll
        for (int kk = 0; kk < 2; ++kk) {
            const int kb = kk * 32 + (l >> 4) * 8;
            bf16x8 af[4], bfr[4];
#pragma unroll
            for (int m = 0; m < 4; ++m) {
                const int row = m * 16 + (l & 15);
                af[m] = *(const bf16x8*)(sA + row * 64 + (kb ^ lswz));
            }
#pragma unroll
            for (int n = 0; n < 4; ++n) {
                const int col = w * 64 + n * 16 + (l & 15);
                bfr[n] = *(const bf16x8*)(sB + col * 64 + (kb ^ lswz));
            }
#pragma unroll
            for (int m = 0; m < 4; ++m)
#pragma unroll
                for (int n = 0; n < 4; ++n)
                    acc[m][n] = __builtin_amdgcn_mfma_f32_16x16x32_bf16(
                        af[m], bfr[n], acc[m][n], 0, 0, 0);
        }
        __syncthreads();
    }

    // --- epilogue: +bias -> LDS bf16 (XOR-swz cols) -> coalesced uint4 stores ---
    float bb[4];
#pragma unroll
    for (int n = 0; n < 4; ++n) bb[n] = bv[w * 64 + n * 16 + (l & 15)];

#pragma unroll
    for (int m = 0; m < 4; ++m) {
#pragma unroll
        for (int n = 0; n < 4; ++n) {
            const int col = w * 64 + n * 16 + (l & 15);
#pragma unroll
            for (int j = 0; j < 4; ++j) {
                const int lr = m * 16 + (l >> 4) * 4 + j;
                sm[lr * 256 + (col ^ ((lr & 7) << 3))] = f2bf(acc[m][n][j] + bb[n]);
            }
        }
    }
    __syncthreads();
#pragma unroll
    for (int i = 0; i < 8; ++i) {
        const int lidx = i * 256 + t;                 // 0..2047 (16B units)
        const int row = lidx >> 5, g = lidx & 31;
        *(uint4*)(v_out + (long)(row0 + row) * 256 + g * 8) =
            *(const uint4*)(sm + row * 256 + ((g * 8) ^ ((row & 7) << 3)));
    }
}

// ---------------------------------------------------------------- K3: sample
// One block per (b,q); 256 threads = 8 heads x 32 dh.
__global__ __launch_bounds__(256) void k_sample(
    const float* __restrict__ refp, const float* __restrict__ off,
    const float* __restrict__ attn, const __hip_bfloat16* __restrict__ v,
    float* __restrict__ out_mid)
{
    __shared__ float soff[256];
    __shared__ float satt[128];
    __shared__ float sref[8];
    const int t = threadIdx.x;
    const int bq = blockIdx.x;
    const int b = bq / NQ_;
    soff[t] = off[bq * 256 + t];
    if (t < 128) satt[t] = attn[bq * 128 + t];
    if (t < 8)   sref[t] = refp[bq * 8 + t];
    __syncthreads();

    const int h = t >> 5, d = t & 31;
    const __hip_bfloat16* vb = v + (long)b * NV_ * 256 + h * 32 + d;
    float acc = 0.f;

    constexpr int HS[4] = {92, 46, 23, 12};
    constexpr int WS_[4] = {160, 80, 40, 20};
    constexpr int ST[4] = {0, 14720, 18400, 19320};
#pragma unroll
    for (int l = 0; l < 4; ++l) {
        const int Hl = HS[l], Wl = WS_[l], st = ST[l];
        const float rx = sref[l * 2 + 0], ry = sref[l * 2 + 1];
#pragma unroll
        for (int p = 0; p < 4; ++p) {
            const int c = h * 32 + l * 8 + p * 2;
            const float x = fmaf(rx, (float)Wl, soff[c])     - 0.5f;
            const float y = fmaf(ry, (float)Hl, soff[c + 1]) - 0.5f;
            const float aw = satt[h * 16 + l * 4 + p];
            const float x0f = floorf(x), y0f = floorf(y);
            const int x0 = (int)x0f, y0 = (int)y0f;
            const float wx1 = x - x0f, wx0 = 1.f - wx1;
            const float wy1 = y - y0f, wy0 = 1.f - wy1;
            const bool vx0 = (x0 >= 0) && (x0 < Wl);
            const bool vx1 = (x0 + 1 >= 0) && (x0 + 1 < Wl);
            if (y0 >= 0 && y0 < Hl) {
                const __hip_bfloat16* rowp = vb + (long)(st + y0 * Wl) * 256;
                if (vx0) acc += __bfloat162float(rowp[(long)x0 * 256])       * (wx0 * wy0 * aw);
                if (vx1) acc += __bfloat162float(rowp[(long)(x0 + 1) * 256]) * (wx1 * wy0 * aw);
            }
            if (y0 + 1 >= 0 && y0 + 1 < Hl) {
                const __hip_bfloat16* rowp = vb + (long)(st + (y0 + 1) * Wl) * 256;
                if (vx0) acc += __bfloat162float(rowp[(long)x0 * 256])       * (wx0 * wy1 * aw);
                if (vx1) acc += __bfloat162float(rowp[(long)(x0 + 1) * 256]) * (wx1 * wy1 * aw);
            }
        }
    }
    out_mid[bq * 256 + t] = acc;
}

// ---------------------------------------------------------------- K4: output
// out = mid @ Wo + bo + query. 16 rows/block, 256 threads.
__global__ __launch_bounds__(256) void k_out(
    const float* __restrict__ mid, const float* __restrict__ Wo,
    const float* __restrict__ bo, const float* __restrict__ query,
    float* __restrict__ out)
{
    __shared__ float sv[16 * 256];
    const int t = threadIdx.x;
    const int row0 = blockIdx.x * 16;
    const float4* src = (const float4*)(mid + row0 * 256);
#pragma unroll
    for (int i = 0; i < 4; ++i) ((float4*)sv)[t + i * 256] = src[t + i * 256];
    __syncthreads();

    float acc[16];
#pragma unroll
    for (int r = 0; r < 16; ++r) acc[r] = 0.f;
    const float* wp = Wo + t;
    for (int kq = 0; kq < 64; ++kq) {
        const float w0 = wp[(kq * 4 + 0) * 256];
        const float w1 = wp[(kq * 4 + 1) * 256];
        const float w2 = wp[(kq * 4 + 2) * 256];
        const float w3 = wp[(kq * 4 + 3) * 256];
#pragma unroll
        for (int r = 0; r < 16; ++r) {
            const float4 a = ((const float4*)(sv + r * 256))[kq];
            acc[r] = fmaf(a.x, w0, fmaf(a.y, w1, fmaf(a.z, w2, fmaf(a.w, w3, acc[r]))));
        }
    }
    const float b = bo[t];
#pragma unroll
    for (int r = 0; r < 16; ++r) {
        const int row = row0 + r;
        out[row * 256 + t] = acc[r] + b + query[row * 256 + t];
    }
}

// ---------------------------------------------------------------- launch
extern "C" void kernel_launch(void* const* d_in, const int* in_sizes, int n_in,
                              void* d_out, int out_size, void* d_ws, size_t ws_size,
                              hipStream_t stream)
{
    const float* query = (const float*)d_in[0];
    const float* value = (const float*)d_in[1];
    const float* refp  = (const float*)d_in[2];
    const float* Wv    = (const float*)d_in[3];
    const float* bv    = (const float*)d_in[4];
    const float* Ws    = (const float*)d_in[5];
    const float* bs    = (const float*)d_in[6];
    const float* Wa    = (const float*)d_in[7];
    const float* ba    = (const float*)d_in[8];
    const float* Wo    = (const float*)d_in[9];
    const float* bo    = (const float*)d_in[10];
    float* out = (float*)d_out;

    char* ws = (char*)d_ws;
    // layout: v(bf16) | off(f32) | attn(f32) | mid(f32) | wvt(bf16 img)
    unsigned short* v_ws = (unsigned short*)ws;                            // 80,117,760 B
    float* off_ws  = (float*)(ws + 80117760);                              //  7,372,800 B
    float* attn_ws = (float*)(ws + 80117760 + 7372800);                    //  3,686,400 B
    float* mid_ws  = (float*)(ws + 80117760 + 7372800 + 3686400);          //  7,372,800 B
    unsigned short* wvt_ws = (unsigned short*)(ws + 80117760 + 7372800 + 3686400 + 7372800); // 131,072 B

    k_wvprep<<<dim3(256), dim3(256), 0, stream>>>(Wv, wvt_ws);
    k_params<<<dim3(B_ * NQ_ / 4), dim3(128), 0, stream>>>(query, Ws, bs, Wa, ba, off_ws, attn_ws);
    k_vgemm <<<dim3(M_TOT / 64), dim3(256), 0, stream>>>(value, wvt_ws, bv, v_ws);
    k_sample<<<dim3(B_ * NQ_), dim3(256), 0, stream>>>(refp, off_ws, attn_ws,
                                                       (const __hip_bfloat16*)v_ws, mid_ws);
    k_out   <<<dim3(B_ * NQ_ / 16), dim3(256), 0, stream>>>(mid_ws, Wo, bo, query, out);
}

// Round 5
// 198.708 us; speedup vs baseline: 2.6558x; 1.0222x over previous
//
#include <hip/hip_runtime.h>
#include <hip/hip_bf16.h>

// Deformable attention (Deformable-DETR) on MI355X.
// Static problem: B=8, NQ=900, E=256, H=8, L=4, P=4, dh=32, NV=19560
// levels (h,w): (92,160) (46,80) (23,40) (12,20); starts 0,14720,18400,19320

#define B_   8
#define NQ_  900
#define E_   256
#define H_   8
#define NV_  19560
#define M_TOT (B_ * NV_)   // 156480 = 64 * 2445 exactly
#define MQ_  (B_ * NQ_)    // 7200 query rows

typedef __attribute__((ext_vector_type(8))) __bf16 bf16x8;
typedef __attribute__((ext_vector_type(4))) float f32x4;

__device__ __forceinline__ unsigned short f2bf(float x) {
    unsigned int u = __builtin_bit_cast(unsigned int, x);
    u += 0x7FFFu + ((u >> 16) & 1u);          // RNE to bf16
    return (unsigned short)(u >> 16);
}

// ---------------------------------------------------------------- K1: params
// off = query@Ws + bs  (256 cols), logits = query@Wa + ba (128 cols),
// softmax over each h's 16 logits. 4 query rows per block, 128 threads.
__global__ __launch_bounds__(128) void k_params(
    const float* __restrict__ query, const float* __restrict__ Ws,
    const float* __restrict__ bs, const float* __restrict__ Wa,
    const float* __restrict__ ba, float* __restrict__ off_out,
    float* __restrict__ attn_out)
{
    __shared__ float sq[4 * 256];
    __shared__ float slog[4 * 128];
    const int t = threadIdx.x;
    const int row0 = blockIdx.x * 4;      // flat (b*NQ+q) base
    const float4* qsrc = (const float4*)(query + row0 * 256);
    for (int i = t; i < 256; i += 128) ((float4*)sq)[i] = qsrc[i];
    __syncthreads();

    float a0[4] = {0,0,0,0}, a1[4] = {0,0,0,0}, a2[4] = {0,0,0,0};
    for (int k = 0; k < 256; ++k) {
        const float w0 = Ws[k * 256 + t];
        const float w1 = Ws[k * 256 + t + 128];
        const float w2 = Wa[k * 128 + t];
#pragma unroll
        for (int r = 0; r < 4; ++r) {
            const float q = sq[r * 256 + k];
            a0[r] = fmaf(q, w0, a0[r]);
            a1[r] = fmaf(q, w1, a1[r]);
            a2[r] = fmaf(q, w2, a2[r]);
        }
    }
    const float b0 = bs[t], b1 = bs[t + 128], b2 = ba[t];
#pragma unroll
    for (int r = 0; r < 4; ++r) {
        off_out[(row0 + r) * 256 + t]       = a0[r] + b0;
        off_out[(row0 + r) * 256 + t + 128] = a1[r] + b1;
        slog[r * 128 + t]                   = a2[r] + b2;
    }
    __syncthreads();
    if (t < 32) {                         // 4 rows x 8 heads
        const int r = t >> 3, h = t & 7;
        const float* pl = slog + r * 128 + h * 16;
        float m = pl[0];
#pragma unroll
        for (int j = 1; j < 16; ++j) m = fmaxf(m, pl[j]);
        float e[16];
        float s = 0.f;
#pragma unroll
        for (int j = 0; j < 16; ++j) { e[j] = expf(pl[j] - m); s += e[j]; }
        const float inv = 1.0f / s;
        float* po = attn_out + (row0 + r) * 128 + h * 16;
#pragma unroll
        for (int j = 0; j < 16; ++j) po[j] = e[j] * inv;
    }
}

// ---------------------------------------------------------------- K2a: W prep
// W^T bf16 image for BK=32 steps, plain layout:
// img[ks(8)][col(256)][rr(32)] = bf16( W[ks*32+rr][col] )
__global__ __launch_bounds__(256) void k_prep(
    const float* __restrict__ W, unsigned short* __restrict__ img)
{
    const int i = blockIdx.x * 256 + threadIdx.x;   // 0..65535
    const int ks  = i >> 13;
    const int col = (i >> 5) & 255;
    const int rr  = i & 31;
    img[i] = f2bf(W[(ks * 32 + rr) * 256 + col]);
}

// ---------------------------------------------------------------- K2b: v proj (MFMA)
// v = value @ Wv + bv, stored bf16. BM=64 x BN=256(full), BK=32 x 8 steps,
// double-buffered 2-phase pipeline (T3-min): issue next-step loads, compute
// current, convert/write next-A, ONE barrier per step. 40KB LDS -> 4 blk/CU.
__global__ __launch_bounds__(256) void k_vgemm(
    const float* __restrict__ value, const unsigned short* __restrict__ wvt,
    const float* __restrict__ bv, unsigned short* __restrict__ v_out)
{
    __shared__ unsigned short sm[20480];          // 40 KB
    unsigned short* const sAb[2] = {sm, sm + 2048};          // 64x32 each
    unsigned short* const sBb[2] = {sm + 4096, sm + 12288};  // 256x32 each

    const int t = threadIdx.x;
    const int w = t >> 6, l = t & 63;             // wave 0..3 owns cols w*64..+63
    const int row0 = blockIdx.x * 64;
    const int ar = t >> 2, akq = t & 3;           // A stage: row, 8-float group
    const float* asrc = value + (long)(row0 + ar) * 256 + akq * 8;
    unsigned short* const adst_off = (unsigned short*)0 + ar * 32 + akq * 8; // offset only

    f32x4 acc[4][4];
#pragma unroll
    for (int m = 0; m < 4; ++m)
#pragma unroll
        for (int n = 0; n < 4; ++n) acc[m][n] = (f32x4){0.f, 0.f, 0.f, 0.f};

    // ---- prologue: stage step 0 ----
    f32x4 a0 = *(const f32x4*)(asrc + 0);
    f32x4 a1 = *(const f32x4*)(asrc + 4);
#pragma unroll
    for (int i = 0; i < 4; ++i)
        __builtin_amdgcn_global_load_lds(
            (const __attribute__((address_space(1))) unsigned int*)(wvt + i * 2048 + t * 8),
            (__attribute__((address_space(3))) unsigned int*)(sBb[0] + i * 2048 + t * 8),
            16, 0, 0);
    {
        unsigned short* dst = sAb[0] + ar * 32 + akq * 8;
        const unsigned int p0 = (unsigned)f2bf(a0.x) | ((unsigned)f2bf(a0.y) << 16);
        const unsigned int p1 = (unsigned)f2bf(a0.z) | ((unsigned)f2bf(a0.w) << 16);
        const unsigned int p2 = (unsigned)f2bf(a1.x) | ((unsigned)f2bf(a1.y) << 16);
        const unsigned int p3 = (unsigned)f2bf(a1.z) | ((unsigned)f2bf(a1.w) << 16);
        *(uint4*)dst = make_uint4(p0, p1, p2, p3);
    }
    __syncthreads();

    const int hi8 = (l >> 4) * 8;
#pragma unroll
    for (int ks = 0; ks < 8; ++ks) {
        unsigned short* const curA = sAb[ks & 1];
        unsigned short* const curB = sBb[ks & 1];
        unsigned short* const nxtA = sAb[(ks & 1) ^ 1];
        unsigned short* const nxtB = sBb[(ks & 1) ^ 1];
        // --- issue next-step loads (fly under compute) ---
        if (ks < 7) {
            a0 = *(const f32x4*)(asrc + (ks + 1) * 32 + 0);
            a1 = *(const f32x4*)(asrc + (ks + 1) * 32 + 4);
#pragma unroll
            for (int i = 0; i < 4; ++i)
                __builtin_amdgcn_global_load_lds(
                    (const __attribute__((address_space(1))) unsigned int*)
                        (wvt + (ks + 1) * 8192 + i * 2048 + t * 8),
                    (__attribute__((address_space(3))) unsigned int*)(nxtB + i * 2048 + t * 8),
                    16, 0, 0);
        }
        // --- compute current step: 16 MFMA / wave ---
        bf16x8 af[4], bfr[4];
#pragma unroll
        for (int m = 0; m < 4; ++m)
            af[m] = *(const bf16x8*)(curA + (m * 16 + (l & 15)) * 32 + hi8);
#pragma unroll
        for (int n = 0; n < 4; ++n)
            bfr[n] = *(const bf16x8*)(curB + (w * 64 + n * 16 + (l & 15)) * 32 + hi8);
#pragma unroll
        for (int m = 0; m < 4; ++m)
#pragma unroll
            for (int n = 0; n < 4; ++n)
                acc[m][n] = __builtin_amdgcn_mfma_f32_16x16x32_bf16(
                    af[m], bfr[n], acc[m][n], 0, 0, 0);
        // --- convert+write next-A (forces wait only on A loads) ---
        if (ks < 7) {
            unsigned short* dst = nxtA + ar * 32 + akq * 8;
            const unsigned int p0 = (unsigned)f2bf(a0.x) | ((unsigned)f2bf(a0.y) << 16);
            const unsigned int p1 = (unsigned)f2bf(a0.z) | ((unsigned)f2bf(a0.w) << 16);
            const unsigned int p2 = (unsigned)f2bf(a1.x) | ((unsigned)f2bf(a1.y) << 16);
            const unsigned int p3 = (unsigned)f2bf(a1.z) | ((unsigned)f2bf(a1.w) << 16);
            *(uint4*)dst = make_uint4(p0, p1, p2, p3);
        }
        __syncthreads();
    }

    // --- epilogue: +bias -> LDS bf16 (XOR-swz cols) -> coalesced uint4 stores ---
    float bb[4];
#pragma unroll
    for (int n = 0; n < 4; ++n) bb[n] = bv[w * 64 + n * 16 + (l & 15)];
#pragma unroll
    for (int m = 0; m < 4; ++m) {
#pragma unroll
        for (int n = 0; n < 4; ++n) {
            const int col = w * 64 + n * 16 + (l & 15);
#pragma unroll
            for (int j = 0; j < 4; ++j) {
                const int lr = m * 16 + (l >> 4) * 4 + j;
                sm[lr * 256 + (col ^ ((lr & 7) << 3))] = f2bf(acc[m][n][j] + bb[n]);
            }
        }
    }
    __syncthreads();
#pragma unroll
    for (int i = 0; i < 8; ++i) {
        const int lidx = i * 256 + t;                 // 0..2047 (16B units)
        const int row = lidx >> 5, g = lidx & 31;
        *(uint4*)(v_out + (long)(row0 + row) * 256 + g * 8) =
            *(const uint4*)(sm + row * 256 + ((g * 8) ^ ((row & 7) << 3)));
    }
}

// ---------------------------------------------------------------- K3: sample
// One block per (b,q); 256 threads = 8 heads x 32 dh. mid stored bf16.
__global__ __launch_bounds__(256) void k_sample(
    const float* __restrict__ refp, const float* __restrict__ off,
    const float* __restrict__ attn, const __hip_bfloat16* __restrict__ v,
    unsigned short* __restrict__ out_mid)
{
    __shared__ float soff[256];
    __shared__ float satt[128];
    __shared__ float sref[8];
    const int t = threadIdx.x;
    const int bq = blockIdx.x;
    const int b = bq / NQ_;
    soff[t] = off[bq * 256 + t];
    if (t < 128) satt[t] = attn[bq * 128 + t];
    if (t < 8)   sref[t] = refp[bq * 8 + t];
    __syncthreads();

    const int h = t >> 5, d = t & 31;
    const __hip_bfloat16* vb = v + (long)b * NV_ * 256 + h * 32 + d;
    float acc = 0.f;

    constexpr int HS[4] = {92, 46, 23, 12};
    constexpr int WS_[4] = {160, 80, 40, 20};
    constexpr int ST[4] = {0, 14720, 18400, 19320};
#pragma unroll
    for (int l = 0; l < 4; ++l) {
        const int Hl = HS[l], Wl = WS_[l], st = ST[l];
        const float rx = sref[l * 2 + 0], ry = sref[l * 2 + 1];
#pragma unroll
        for (int p = 0; p < 4; ++p) {
            const int c = h * 32 + l * 8 + p * 2;
            const float x = fmaf(rx, (float)Wl, soff[c])     - 0.5f;
            const float y = fmaf(ry, (float)Hl, soff[c + 1]) - 0.5f;
            const float aw = satt[h * 16 + l * 4 + p];
            const float x0f = floorf(x), y0f = floorf(y);
            const int x0 = (int)x0f, y0 = (int)y0f;
            const float wx1 = x - x0f, wx0 = 1.f - wx1;
            const float wy1 = y - y0f, wy0 = 1.f - wy1;
            const bool vx0 = (x0 >= 0) && (x0 < Wl);
            const bool vx1 = (x0 + 1 >= 0) && (x0 + 1 < Wl);
            if (y0 >= 0 && y0 < Hl) {
                const __hip_bfloat16* rowp = vb + (long)(st + y0 * Wl) * 256;
                if (vx0) acc += __bfloat162float(rowp[(long)x0 * 256])       * (wx0 * wy0 * aw);
                if (vx1) acc += __bfloat162float(rowp[(long)(x0 + 1) * 256]) * (wx1 * wy0 * aw);
            }
            if (y0 + 1 >= 0 && y0 + 1 < Hl) {
                const __hip_bfloat16* rowp = vb + (long)(st + (y0 + 1) * Wl) * 256;
                if (vx0) acc += __bfloat162float(rowp[(long)x0 * 256])       * (wx0 * wy1 * aw);
                if (vx1) acc += __bfloat162float(rowp[(long)(x0 + 1) * 256]) * (wx1 * wy1 * aw);
            }
        }
    }
    out_mid[bq * 256 + t] = f2bf(acc);
}

// ---------------------------------------------------------------- K4: out GEMM (MFMA)
// out = mid(bf16) @ Wo + bo + query. Same pipelined structure as k_vgemm,
// but A stages via pure global_load_lds (mid already bf16). M=7200 (tail block).
__global__ __launch_bounds__(256) void k_ogemm(
    const unsigned short* __restrict__ mid, const unsigned short* __restrict__ wot,
    const float* __restrict__ bo, const float* __restrict__ query,
    float* __restrict__ out)
{
    __shared__ unsigned short sm[20480];
    unsigned short* const sAb[2] = {sm, sm + 2048};
    unsigned short* const sBb[2] = {sm + 4096, sm + 12288};

    const int t = threadIdx.x;
    const int w = t >> 6, l = t & 63;
    const int row0 = blockIdx.x * 64;
    // lane t stages mid[(row0 + t>>2)][ks*32 + (t&3)*8 ..+7] -> LDS linear t*16B
    const unsigned short* amsrc = mid + (long)(row0 + (t >> 2)) * 256 + (t & 3) * 8;

    f32x4 acc[4][4];
#pragma unroll
    for (int m = 0; m < 4; ++m)
#pragma unroll
        for (int n = 0; n < 4; ++n) acc[m][n] = (f32x4){0.f, 0.f, 0.f, 0.f};

    // ---- prologue: stage step 0 ----
    __builtin_amdgcn_global_load_lds(
        (const __attribute__((address_space(1))) unsigned int*)(amsrc),
        (__attribute__((address_space(3))) unsigned int*)(sAb[0] + t * 8), 16, 0, 0);
#pragma unroll
    for (int i = 0; i < 4; ++i)
        __builtin_amdgcn_global_load_lds(
            (const __attribute__((address_space(1))) unsigned int*)(wot + i * 2048 + t * 8),
            (__attribute__((address_space(3))) unsigned int*)(sBb[0] + i * 2048 + t * 8),
            16, 0, 0);
    __syncthreads();

    const int hi8 = (l >> 4) * 8;
#pragma unroll
    for (int ks = 0; ks < 8; ++ks) {
        unsigned short* const curA = sAb[ks & 1];
        unsigned short* const curB = sBb[ks & 1];
        unsigned short* const nxtA = sAb[(ks & 1) ^ 1];
        unsigned short* const nxtB = sBb[(ks & 1) ^ 1];
        if (ks < 7) {
            __builtin_amdgcn_global_load_lds(
                (const __attribute__((address_space(1))) unsigned int*)(amsrc + (ks + 1) * 32),
                (__attribute__((address_space(3))) unsigned int*)(nxtA + t * 8), 16, 0, 0);
#pragma unroll
            for (int i = 0; i < 4; ++i)
                __builtin_amdgcn_global_load_lds(
                    (const __attribute__((address_space(1))) unsigned int*)
                        (wot + (ks + 1) * 8192 + i * 2048 + t * 8),
                    (__attribute__((address_space(3))) unsigned int*)(nxtB + i * 2048 + t * 8),
                    16, 0, 0);
        }
        bf16x8 af[4], bfr[4];
#pragma unroll
        for (int m = 0; m < 4; ++m)
            af[m] = *(const bf16x8*)(curA + (m * 16 + (l & 15)) * 32 + hi8);
#pragma unroll
        for (int n = 0; n < 4; ++n)
            bfr[n] = *(const bf16x8*)(curB + (w * 64 + n * 16 + (l & 15)) * 32 + hi8);
#pragma unroll
        for (int m = 0; m < 4; ++m)
#pragma unroll
            for (int n = 0; n < 4; ++n)
                acc[m][n] = __builtin_amdgcn_mfma_f32_16x16x32_bf16(
                    af[m], bfr[n], acc[m][n], 0, 0, 0);
        __syncthreads();
    }

    // --- epilogue: +bias +residual, guarded fp32 coalesced stores ---
#pragma unroll
    for (int n = 0; n < 4; ++n) {
        const int col = w * 64 + n * 16 + (l & 15);
        const float bb = bo[col];
#pragma unroll
        for (int m = 0; m < 4; ++m) {
#pragma unroll
            for (int j = 0; j < 4; ++j) {
                const int row = row0 + m * 16 + (l >> 4) * 4 + j;
                if (row < MQ_)
                    out[(long)row * 256 + col] =
                        acc[m][n][j] + bb + query[(long)row * 256 + col];
            }
        }
    }
}

// ---------------------------------------------------------------- launch
extern "C" void kernel_launch(void* const* d_in, const int* in_sizes, int n_in,
                              void* d_out, int out_size, void* d_ws, size_t ws_size,
                              hipStream_t stream)
{
    const float* query = (const float*)d_in[0];
    const float* value = (const float*)d_in[1];
    const float* refp  = (const float*)d_in[2];
    const float* Wv    = (const float*)d_in[3];
    const float* bv    = (const float*)d_in[4];
    const float* Ws    = (const float*)d_in[5];
    const float* bs    = (const float*)d_in[6];
    const float* Wa    = (const float*)d_in[7];
    const float* ba    = (const float*)d_in[8];
    const float* Wo    = (const float*)d_in[9];
    const float* bo    = (const float*)d_in[10];
    float* out = (float*)d_out;

    char* ws = (char*)d_ws;
    // layout: v(bf16) | off(f32) | attn(f32) | mid(bf16) | wvt img | wot img
    unsigned short* v_ws = (unsigned short*)ws;                            // 80,117,760 B
    float* off_ws  = (float*)(ws + 80117760);                              //  7,372,800 B
    float* attn_ws = (float*)(ws + 80117760 + 7372800);                    //  3,686,400 B
    unsigned short* mid_ws = (unsigned short*)(ws + 80117760 + 7372800 + 3686400); // 3,686,400 B
    unsigned short* wvt_ws = (unsigned short*)(ws + 80117760 + 7372800 + 3686400 + 3686400); // 131,072 B
    unsigned short* wot_ws = (unsigned short*)(ws + 80117760 + 7372800 + 3686400 + 3686400 + 131072); // 131,072 B

    k_prep  <<<dim3(256), dim3(256), 0, stream>>>(Wv, wvt_ws);
    k_prep  <<<dim3(256), dim3(256), 0, stream>>>(Wo, wot_ws);
    k_params<<<dim3(MQ_ / 4), dim3(128), 0, stream>>>(query, Ws, bs, Wa, ba, off_ws, attn_ws);
    k_vgemm <<<dim3(M_TOT / 64), dim3(256), 0, stream>>>(value, wvt_ws, bv, v_ws);
    k_sample<<<dim3(MQ_), dim3(256), 0, stream>>>(refp, off_ws, attn_ws,
                                                  (const __hip_bfloat16*)v_ws, mid_ws);
    k_ogemm <<<dim3((MQ_ + 63) / 64), dim3(256), 0, stream>>>(mid_ws, wot_ws, bo, query, out);
}